// Round 1
// baseline (5300.864 us; speedup 1.0000x reference)
//
#include <hip/hip_runtime.h>
#include <cmath>

#ifndef M_PI
#define M_PI 3.14159265358979323846
#endif

#define T_LEN   160000
#define NSEG    155
#define ROWS    32
#define NBANDS  8

struct AllCoefs {
    float h[NBANDS][5];   // b0 b1 b2 a1 a2 (a0-normalized, f32-cast like np.float32)
    float l[NBANDS][5];
};

// ======================================================================
// Legacy 3-wave kernel (verified bit-exact) — kept as ws_size fallback
// ======================================================================
#define CHUNK   256
#define NSUB    4
#define NQ      16
#define QPC     64
#define NCHUNK  624
#define TOT_IT  (NCHUNK + 2)
#define LOUD_FLOATS (NBANDS * 2 * ROWS * NSEG)

__device__ __forceinline__ void barrier_lds_only() {
    asm volatile("s_waitcnt lgkmcnt(0)\n\ts_barrier" ::: "memory");
}

__global__ __launch_bounds__(192, 1)
void tf_pipe3_kernel(const float* __restrict__ sig, const float* __restrict__ wm,
                     float* __restrict__ loud, AllCoefs C) {
    __shared__ float I1[2][CHUNK * 32];
    __shared__ float I2[2][CHUNK * 32];

    const int band = blockIdx.x;
    const int src  = blockIdx.y;
    const int tid  = threadIdx.x;
    const int wid  = tid >> 6;
    const int lane = tid & 63;
    const int ch   = lane & 31;

    const float hb0 = C.h[band][0], hb1 = C.h[band][1], hb2 = C.h[band][2];
    const float hna1 = -C.h[band][3], hna2 = -C.h[band][4];
    const float lb0 = C.l[band][0], lb1 = C.l[band][1], lb2 = C.l[band][2];
    const float lna1 = -C.l[band][3], lna2 = -C.l[band][4];
    const float NA1 =  1.79999995231628417969f;
    const float NA2 = -0.810000002384185791f;

    const float* __restrict__ xrow = (src ? wm : sig) + (size_t)ch * T_LEN;
    const float4* __restrict__ xq  = (const float4*)xrow;

    float x1 = 0.f, x2 = 0.f, y1 = 0.f, y2 = 0.f, acc = 0.f;

    float4 pfA[NQ], pfB[NQ];
    if (wid == 0 && lane < 32) {
        #pragma unroll
        for (int i = 0; i < NQ; ++i) pfA[i] = xq[i];
    }

#define HP1(xx, oo)                                                          \
    {  float s1 = __fmaf_rn(hb0, xx, __fmul_rn(hb1, x1));                    \
       float s2 = __fmaf_rn(hb2, x2, s1); x2 = x1; x1 = xx;                  \
       float s3 = __fmaf_rn(hna1, y1, s2);                                   \
       oo = __fmaf_rn(hna2, y2, s3); y2 = y1; y1 = oo; }

#define W0SUB(USE, FILL, cc, s, NEXTQ)                                       \
    {                                                                        \
        float4* __restrict__ ob = (float4*)I1[(cc) & 1];                     \
        _Pragma("unroll")                                                    \
        for (int i = 0; i < NQ; ++i) {                                       \
            float4 v = USE[i];                                               \
            FILL[i] = xq[(NEXTQ) + i];                                       \
            float4 o;                                                        \
            HP1(v.x, o.x) HP1(v.y, o.y) HP1(v.z, o.z) HP1(v.w, o.w)          \
            ob[((s) * NQ + i) * 32 + ch] = o;                                \
        }                                                                    \
    }

    for (int iter = 0; iter < TOT_IT; ++iter) {
        if (wid == 0) {
            if (iter < NCHUNK && lane < 32) {
                const int c = iter;
                const int q0 = c * QPC;
                W0SUB(pfA, pfB, c, 0, q0 + 1 * NQ)
                W0SUB(pfB, pfA, c, 1, q0 + 2 * NQ)
                W0SUB(pfA, pfB, c, 2, q0 + 3 * NQ)
                W0SUB(pfB, pfA, c, 3, q0 + 4 * NQ)
            }
        } else if (wid == 1) {
            if (iter >= 1 && iter <= NCHUNK && lane < 32) {
                const int c = iter - 1;
                const float4* __restrict__ ib = (const float4*)I1[c & 1];
                float4* __restrict__ ob = (float4*)I2[c & 1];
                #pragma unroll
                for (int s = 0; s < NSUB; ++s) {
                    float4 v[NQ];
                    #pragma unroll
                    for (int i = 0; i < NQ; ++i) v[i] = ib[(s * NQ + i) * 32 + ch];
                    #pragma unroll
                    for (int i = 0; i < NQ; ++i) {
                        float4 o;
                        #define LP1(xx, oo) \
                            { float s1 = __fmaf_rn(lb0, xx, __fmul_rn(lb1, x1)); \
                              float s2 = __fmaf_rn(lb2, x2, s1); x2 = x1; x1 = xx; \
                              float s3 = __fmaf_rn(lna1, y1, s2); \
                              oo = __fmaf_rn(lna2, y2, s3); y2 = y1; y1 = oo; }
                        LP1(v[i].x, o.x) LP1(v[i].y, o.y) LP1(v[i].z, o.z) LP1(v[i].w, o.w)
                        #undef LP1
                        ob[(s * NQ + i) * 32 + ch] = o;
                    }
                }
            }
        } else {
            if (iter >= 2) {
                const int c = iter - 2;
                const bool evenHalf = (lane < 32);
                const float4* __restrict__ ib = (const float4*)I2[c & 1];
                #pragma unroll
                for (int s = 0; s < NSUB; ++s) {
                    const int u = c * NSUB + s;
                    const int m32 = u & 31;
                    if ((m32 == (evenHalf ? 0 : 16)) && (u >> 4) < NSEG) {
                        x1 = 0.f; x2 = 0.f; y1 = 0.f; y2 = 0.f; acc = 0.f;
                    }
                    float4 v[NQ];
                    #pragma unroll
                    for (int i = 0; i < NQ; ++i) v[i] = ib[(s * NQ + i) * 32 + ch];
                    #pragma unroll
                    for (int i = 0; i < NQ; ++i) {
                        float s1, s2, s3, yy;
                        #define WSTEP(xx) \
                            s1 = __fmaf_rn(-2.0f, x1, xx); \
                            s2 = __fadd_rn(s1, x2); \
                            s3 = __fmaf_rn(NA1, y1, s2); \
                            yy = __fmaf_rn(NA2, y2, s3); \
                            x2 = x1; x1 = xx; y2 = y1; y1 = yy; \
                            acc = __fmaf_rn(yy, yy, acc);
                        WSTEP(v[i].x) WSTEP(v[i].y) WSTEP(v[i].z) WSTEP(v[i].w)
                        #undef WSTEP
                    }
                    const int endm = evenHalf ? 31 : 15;
                    if (m32 == endm && u >= 31) {
                        const int j = (u - 31) >> 4;
                        float e = __fmul_rn(acc, 0.00048828125f);
                        loud[((size_t)((band * 2 + src) * ROWS + ch)) * NSEG + j] =
                            __fmul_rn(10.0f, log10f(__fadd_rn(e, 1e-8f)));
                    }
                }
            }
        }
        barrier_lds_only();
    }
#undef W0SUB
#undef HP1
}

// ======================================================================
// R1: 6-wave FIR/REC-split pipeline, interfaces in global L2 rings.
//
// One block per (band,src), 6 waves, chunk = 512 samples, 312 barriers
// (vs 626). Each biquad's per-sample op sequence is split across two
// waves with the EXACT same FMA order as the verified kernel:
//   FIR: s2 = fma(b2,x2, fma(b0,x, mul(b1,x1)))      (3 VALU)
//   REC: y  = fma(na2,y2, fma(na1,y1, s2))           (2 VALU)
// so every wave is <=3 VALU/sample (<=6 issue cyc on SIMD32), at/below
// the 8-cyc dep-chain floor. Streams hand off through 2-slot global ring
// buffers (same-CU L1/L2 coherent: write-through stores + vmcnt drain +
// s_barrier). No LDS at all -> no LDS-pipe contention, no lgkm drains.
//
//   w0 FIR_hp : HBM x        -> fhp ring   (counted vmcnt(16) barrier:
//               next-chunk prefetch stays in flight across the barrier)
//   w1 REC_hp : fhp -> yhp
//   w2 FIR_lp : yhp -> flp
//   w3 REC_lp : flp -> ylp
//   w4 FIR_w  : ylp -> fw (64-wide; lanes 0-31 even-, 32-63 odd-parity;
//               x1/x2 reset at c%4==0/2 — segment bounds align to chunks)
//   w5 REC_w  : fw  -> acc -> loud (write at c%4==3/1, j=(c-3)/2)
// ======================================================================
#define CH6     512
#define QPC6    128                // float4 quads per chunk
#define NCH6    312                // 512*312 = 159744 = all samples used
#define TOT6    (NCH6 + 5)         // 6-wave pipeline skew drain
#define LOUD_F4 19840              // loud region = 79360 floats = 19840 f4
#define SLOT32  4096               // f4 per slot, 32-wide iface (128q*32)
#define SLOT64  8192
#define R32Q    (2 * SLOT32)       // f4 per block per 32-wide iface
#define R64Q    (2 * SLOT64)
#define WS_NEED6 ((size_t)(LOUD_F4 + 64 * R32Q + 16 * R64Q) * 16)  // ~12.9 MB

__device__ __forceinline__ void bar_vm0() {
    asm volatile("s_waitcnt vmcnt(0)\n\ts_barrier" ::: "memory");
}

// FIR part of a biquad (3 VALU), updates x1,x2
#define FIR3(B0, B1, B2, xx, oo) { \
    float s1_ = __fmaf_rn(B0, xx, __fmul_rn(B1, x1)); \
    oo = __fmaf_rn(B2, x2, s1_); x2 = x1; x1 = xx; }

// REC part of a biquad (2 VALU), updates y1,y2
#define REC2(A1, A2, ff, oo) { \
    float s3_ = __fmaf_rn(A1, y1, ff); \
    oo = __fmaf_rn(A2, y2, s3_); y2 = y1; y1 = oo; }

// weighting FIR: s2 = (x - 2*x1) + x2   (fma product exact -> bit-identical)
#define FIRW(xx, oo) { \
    float s1_ = __fmaf_rn(-2.0f, x1, xx); \
    oo = __fadd_rn(s1_, x2); x2 = x1; x1 = xx; }

// weighting REC + energy acc (3 VALU)
#define RECW(ff) { \
    float s3_ = __fmaf_rn(NA1, y1, ff); \
    float yy_ = __fmaf_rn(NA2, y2, s3_); \
    y2 = y1; y1 = yy_; acc = __fmaf_rn(yy_, yy_, acc); }

// Generic chunk body: prologue-load sub0, then 4 sub-pairs with ping-pong
// register prefetch of the next sub-chunk. sp-loop deliberately NOT
// unrolled (I-cache); i-loops fully unrolled (static pfA/pfB indexing).
#define PIPE_BODY(IBQ, OBQ, STEP4)                                        \
    {                                                                     \
        _Pragma("unroll")                                                 \
        for (int i = 0; i < 16; ++i) pfA[i] = IBQ(i);                     \
        _Pragma("nounroll")                                               \
        for (int sp = 0; sp < 4; ++sp) {                                  \
            const int qA = sp * 32;                                       \
            _Pragma("unroll")                                             \
            for (int i = 0; i < 16; ++i) {                                \
                float4 v = pfA[i];                                        \
                pfB[i] = IBQ(qA + 16 + i);                                \
                float4 o; STEP4(v, o);                                    \
                OBQ(qA + i, o);                                           \
            }                                                             \
            _Pragma("unroll")                                             \
            for (int i = 0; i < 16; ++i) {                                \
                float4 v = pfB[i];                                        \
                if (sp < 3) pfA[i] = IBQ(qA + 32 + i);                    \
                float4 o; STEP4(v, o);                                    \
                OBQ(qA + 16 + i, o);                                      \
            }                                                             \
        }                                                                 \
    }

__global__ __launch_bounds__(384, 1)
void tf_pipe6_kernel(const float* __restrict__ sig, const float* __restrict__ wm,
                     float* __restrict__ ws, AllCoefs C) {
    const int band = blockIdx.x;
    const int src  = blockIdx.y;
    const int blk  = src * NBANDS + band;     // 0..15
    const int tid  = threadIdx.x;
    const int wid  = tid >> 6;                // 0..5
    const int lane = tid & 63;
    const int ch   = lane & 31;               // chain = batch row

    float*  loud = ws;
    float4* ring = (float4*)ws + LOUD_F4;
    float4* fhp  = ring               + (size_t)blk * R32Q;
    float4* yhp  = ring + 16 * R32Q   + (size_t)blk * R32Q;
    float4* flp  = ring + 32 * R32Q   + (size_t)blk * R32Q;
    float4* ylp  = ring + 48 * R32Q   + (size_t)blk * R32Q;
    float4* fw   = ring + 64 * R32Q   + (size_t)blk * R64Q;

    const float hb0 = C.h[band][0], hb1 = C.h[band][1], hb2 = C.h[band][2];
    const float hna1 = -C.h[band][3], hna2 = -C.h[band][4];
    const float lb0 = C.l[band][0], lb1 = C.l[band][1], lb2 = C.l[band][2];
    const float lna1 = -C.l[band][3], lna2 = -C.l[band][4];
    const float NA1 =  1.79999995231628417969f; // -np.float32(-1.8)
    const float NA2 = -0.810000002384185791f;   // -np.float32(0.81)

    const float* __restrict__ xrow = (src ? wm : sig) + (size_t)ch * T_LEN;
    const float4* __restrict__ xq  = (const float4*)xrow;

    float x1 = 0.f, x2 = 0.f, y1 = 0.f, y2 = 0.f, acc = 0.f;
    float4 pfA[16], pfB[16];

    if (wid == 0 && lane < 32) {
        #pragma unroll
        for (int i = 0; i < 16; ++i) pfA[i] = xq[i];   // chunk 0, sub 0
    }

    for (int it = 0; it < TOT6; ++it) {
        if (wid == 0) {
            // -------- FIR_hp: global x -> fhp --------
            const int c = it;
            if (c < NCH6 && lane < 32) {
                const int gq0 = c * QPC6;
                float4* __restrict__ ob = fhp + (c & 1) * SLOT32;
                #pragma nounroll
                for (int sp = 0; sp < 4; ++sp) {
                    const int qA = sp * 32;
                    #pragma unroll
                    for (int i = 0; i < 16; ++i) {
                        float4 v = pfA[i];
                        pfB[i] = xq[gq0 + qA + 16 + i];
                        float4 o;
                        FIR3(hb0, hb1, hb2, v.x, o.x) FIR3(hb0, hb1, hb2, v.y, o.y)
                        FIR3(hb0, hb1, hb2, v.z, o.z) FIR3(hb0, hb1, hb2, v.w, o.w)
                        ob[(qA + i) * 32 + ch] = o;
                    }
                    #pragma unroll
                    for (int i = 0; i < 16; ++i) {
                        float4 v = pfB[i];
                        if (sp < 3) pfA[i] = xq[gq0 + qA + 32 + i];
                        float4 o;
                        FIR3(hb0, hb1, hb2, v.x, o.x) FIR3(hb0, hb1, hb2, v.y, o.y)
                        FIR3(hb0, hb1, hb2, v.z, o.z) FIR3(hb0, hb1, hb2, v.w, o.w)
                        ob[(qA + 16 + i) * 32 + ch] = o;
                    }
                }
                // Next-chunk sub0 prefetch AFTER all stores (sched_barrier
                // pins issue order), so vmcnt(16) below proves all ring
                // stores drained while the 16 fresh loads stay in flight
                // across the barrier. Max reach: c=311 -> quads 39936..39951
                // -> sample 159807 < 160000 (in-bounds read).
                __builtin_amdgcn_sched_barrier(0);
                #pragma unroll
                for (int i = 0; i < 16; ++i) pfA[i] = xq[gq0 + QPC6 + i];
            }
            asm volatile("s_waitcnt vmcnt(16)\n\ts_barrier" ::: "memory");
        } else if (wid == 1) {
            // -------- REC_hp: fhp -> yhp --------
            const int c = it - 1;
            if (c >= 0 && c < NCH6 && lane < 32) {
                const float4* __restrict__ ib = fhp + (c & 1) * SLOT32;
                float4* __restrict__ ob = yhp + (c & 1) * SLOT32;
                #define IBQ1(q)    ib[(q) * 32 + ch]
                #define OBQ1(q, o) ob[(q) * 32 + ch] = (o)
                #define STEP1(v, o) { REC2(hna1, hna2, v.x, o.x) REC2(hna1, hna2, v.y, o.y) \
                                      REC2(hna1, hna2, v.z, o.z) REC2(hna1, hna2, v.w, o.w) }
                PIPE_BODY(IBQ1, OBQ1, STEP1)
            }
            bar_vm0();
        } else if (wid == 2) {
            // -------- FIR_lp: yhp -> flp --------
            const int c = it - 2;
            if (c >= 0 && c < NCH6 && lane < 32) {
                const float4* __restrict__ ib = yhp + (c & 1) * SLOT32;
                float4* __restrict__ ob = flp + (c & 1) * SLOT32;
                #define IBQ2(q)    ib[(q) * 32 + ch]
                #define OBQ2(q, o) ob[(q) * 32 + ch] = (o)
                #define STEP2(v, o) { FIR3(lb0, lb1, lb2, v.x, o.x) FIR3(lb0, lb1, lb2, v.y, o.y) \
                                      FIR3(lb0, lb1, lb2, v.z, o.z) FIR3(lb0, lb1, lb2, v.w, o.w) }
                PIPE_BODY(IBQ2, OBQ2, STEP2)
            }
            bar_vm0();
        } else if (wid == 3) {
            // -------- REC_lp: flp -> ylp --------
            const int c = it - 3;
            if (c >= 0 && c < NCH6 && lane < 32) {
                const float4* __restrict__ ib = flp + (c & 1) * SLOT32;
                float4* __restrict__ ob = ylp + (c & 1) * SLOT32;
                #define IBQ3(q)    ib[(q) * 32 + ch]
                #define OBQ3(q, o) ob[(q) * 32 + ch] = (o)
                #define STEP3(v, o) { REC2(lna1, lna2, v.x, o.x) REC2(lna1, lna2, v.y, o.y) \
                                      REC2(lna1, lna2, v.z, o.z) REC2(lna1, lna2, v.w, o.w) }
                PIPE_BODY(IBQ3, OBQ3, STEP3)
            }
            bar_vm0();
        } else if (wid == 4) {
            // -------- FIR_w: ylp -> fw (dual parity, 64 lanes) --------
            const int c = it - 4;
            if (c >= 0 && c < NCH6) {
                // segment starts: even parity at c%4==0, odd at c%4==2
                if ((c & 3) == (lane < 32 ? 0 : 2)) { x1 = 0.f; x2 = 0.f; }
                const float4* __restrict__ ib = ylp + (c & 1) * SLOT32;
                float4* __restrict__ ob = fw + (c & 1) * SLOT64;
                #define IBQ4(q)    ib[(q) * 32 + ch]
                #define OBQ4(q, o) ob[(q) * 64 + lane] = (o)
                #define STEP4W(v, o) { FIRW(v.x, o.x) FIRW(v.y, o.y) FIRW(v.z, o.z) FIRW(v.w, o.w) }
                PIPE_BODY(IBQ4, OBQ4, STEP4W)
            }
            bar_vm0();
        } else {
            // -------- REC_w + energy: fw -> loud (dual parity) --------
            const int c = it - 5;
            if (c >= 0 && c < NCH6) {
                const bool ev = (lane < 32);
                if ((c & 3) == (ev ? 0 : 2)) { y1 = 0.f; y2 = 0.f; acc = 0.f; }
                const float4* __restrict__ ib = fw + (c & 1) * SLOT64;
                #define IBQ5(q)    ib[(q) * 64 + lane]
                #define OBQ5(q, o) (void)(o)
                #define STEP5(v, o) { RECW(v.x) RECW(v.y) RECW(v.z) RECW(v.w) (void)o; }
                PIPE_BODY(IBQ5, OBQ5, STEP5)
                // even segs end at c%4==3 (j=(c-3)/2 even), odd at c%4==1
                if (c >= 3 && (c & 3) == (ev ? 3 : 1)) {
                    const int j = (c - 3) >> 1;
                    float e = __fmul_rn(acc, 0.00048828125f);   // /2048 exact
                    loud[((size_t)((band * 2 + src) * ROWS + ch)) * NSEG + j] =
                        __fmul_rn(10.0f, log10f(__fadd_rn(e, 1e-8f)));
                }
            }
            bar_vm0();
        }
    }
}

// ======================================================================
__global__ __launch_bounds__(256)
void tf_reduce_kernel(const float* __restrict__ loud, float* __restrict__ out) {
    __shared__ double sh[256];
    const int per_band = ROWS * NSEG;       // 4960
    const int npairs   = NBANDS * per_band; // 39680
    double s = 0.0;
    for (int idx = threadIdx.x; idx < npairs; idx += 256) {
        int band = idx / per_band;
        int rs   = idx - band * per_band;
        float a = loud[(size_t)(band * 2 + 0) * per_band + rs];
        float b = loud[(size_t)(band * 2 + 1) * per_band + rs];
        s += fabs((double)b - (double)a);
    }
    sh[threadIdx.x] = s;
    __syncthreads();
    for (int off = 128; off > 0; off >>= 1) {
        if (threadIdx.x < off) sh[threadIdx.x] += sh[threadIdx.x + off];
        __syncthreads();
    }
    if (threadIdx.x == 0) out[0] = (float)(sh[0] / (double)npairs);
}

// Host-side coefficients: f64 with the reference's exact expression order,
// then cast each to f32 (mirrors tuple(np.float32(v / a0) ...)).
static void mk_hp(double cutoff, float* o) {
    const double w0    = 2.0 * M_PI * cutoff / 16000.0;
    const double alpha = sin(w0) / (2.0 * 0.707);
    const double cw    = cos(w0);
    const double b0 = (1.0 + cw) / 2.0;
    const double b1 = -(1.0 + cw);
    const double b2 = (1.0 + cw) / 2.0;
    const double a0 = 1.0 + alpha;
    const double a1 = -2.0 * cw;
    const double a2 = 1.0 - alpha;
    o[0] = (float)(b0 / a0); o[1] = (float)(b1 / a0); o[2] = (float)(b2 / a0);
    o[3] = (float)(a1 / a0); o[4] = (float)(a2 / a0);
}

static void mk_lp(double cutoff, float* o) {
    const double w0    = 2.0 * M_PI * cutoff / 16000.0;
    const double alpha = sin(w0) / (2.0 * 0.707);
    const double cw    = cos(w0);
    const double b0 = (1.0 - cw) / 2.0;
    const double b1 = 1.0 - cw;
    const double b2 = (1.0 - cw) / 2.0;
    const double a0 = 1.0 + alpha;
    const double a1 = -2.0 * cw;
    const double a2 = 1.0 - alpha;
    o[0] = (float)(b0 / a0); o[1] = (float)(b1 / a0); o[2] = (float)(b2 / a0);
    o[3] = (float)(a1 / a0); o[4] = (float)(a2 / a0);
}

extern "C" void kernel_launch(void* const* d_in, const int* in_sizes, int n_in,
                              void* d_out, int out_size, void* d_ws, size_t ws_size,
                              hipStream_t stream) {
    const float* sig = (const float*)d_in[0];
    const float* wm  = (const float*)d_in[1];

    AllCoefs C;
    for (int i = 0; i < NBANDS; ++i) {
        mk_hp(1000.0 * (double)i,       C.h[i]);
        mk_lp(1000.0 * (double)(i + 1), C.l[i]);
    }

    if (ws_size >= WS_NEED6) {
        // 6-wave FIR/REC-split pipeline, rings in workspace (~12.9 MB)
        tf_pipe6_kernel<<<dim3(NBANDS, 2), 384, 0, stream>>>(
            sig, wm, (float*)d_ws, C);
    } else {
        // workspace too small for rings: verified 3-wave fallback
        tf_pipe3_kernel<<<dim3(NBANDS, 2), 192, 0, stream>>>(
            sig, wm, (float*)d_ws, C);
    }
    tf_reduce_kernel<<<1, 256, 0, stream>>>((const float*)d_ws, (float*)d_out);
}

// Round 2
// 2375.003 us; speedup vs baseline: 2.2319x; 2.2319x over previous
//
#include <hip/hip_runtime.h>
#include <cmath>

#ifndef M_PI
#define M_PI 3.14159265358979323846
#endif

#define T_LEN   160000
#define NSEG    155
#define ROWS    32
#define NBANDS  8

#define CHUNK   256                  // samples per barrier interval
#define NSUB    4                    // sub-chunks of 64
#define NQ      16                   // float4 quads per sub-chunk
#define QPC     64                   // quads per chunk
#define NCHUNK  624                  // 256*624 = 159744 = all samples any segment uses
#define TOT_IT  (NCHUNK + 2)         // 3-stage pipeline drain
#define LOUD_FLOATS (NBANDS * 2 * ROWS * NSEG)   // 79360

struct AllCoefs {
    float h[NBANDS][5];   // b0 b1 b2 a1 a2 (a0-normalized, f32-cast like np.float32)
    float l[NBANDS][5];
};

// Workgroup barrier without the vmcnt(0) drain (only LDS carries inter-wave
// data; w0's global prefetch stays in flight across the barrier).
__device__ __forceinline__ void barrier_lds_only() {
    asm volatile("s_waitcnt lgkmcnt(0)\n\ts_barrier" ::: "memory");
}

// ============================ Fused pipeline =============================
// One block per (band, src): 32 chains, 3 waves. 256 samples per barrier.
//   w0 : hpFIR + hpREC   global x (sub-chunk ping-pong prefetch) -> I1
//   w1 : lpFIR + lpREC   I1 -> I2
//   w2 : weighting, dual parity: lanes 0-31 even segments, 32-63 odd
// R2 change (I$-thrash theory): the previously fully-unrolled stage bodies
// (~34 KB combined, > 32 KB per-CU I$) are re-rolled at sub-chunk
// granularity (w0: 2-iter pair loop preserving the pfA/pfB ping-pong;
// w1/w2: 4/4-iter sub-chunk loops). Inner 16-quad loops stay unrolled.
// Hot-loop code ~12 KB -> fits I$. Per-lane arithmetic ops and their ORDER
// are bit-identical to the kernel verified BIT-EXACT (absmax 0.0).
__global__ __launch_bounds__(192, 1)
void tf_pipe3_kernel(const float* __restrict__ sig, const float* __restrict__ wm,
                     float* __restrict__ loud, AllCoefs C) {
    __shared__ float I1[2][CHUNK * 32];   // hp -> lp       (64 KiB)
    __shared__ float I2[2][CHUNK * 32];   // lp -> weight   (64 KiB)

    const int band = blockIdx.x;
    const int src  = blockIdx.y;              // 0 = signal, 1 = watermark
    const int tid  = threadIdx.x;
    const int wid  = tid >> 6;
    const int lane = tid & 63;
    const int ch   = lane & 31;               // chain = batch row

    const float hb0 = C.h[band][0], hb1 = C.h[band][1], hb2 = C.h[band][2];
    const float hna1 = -C.h[band][3], hna2 = -C.h[band][4];
    const float lb0 = C.l[band][0], lb1 = C.l[band][1], lb2 = C.l[band][2];
    const float lna1 = -C.l[band][3], lna2 = -C.l[band][4];
    const float NA1 =  1.79999995231628417969f; // -np.float32(-1.8)
    const float NA2 = -0.810000002384185791f;   // -np.float32(0.81)

    const float* __restrict__ xrow = (src ? wm : sig) + (size_t)ch * T_LEN;
    const float4* __restrict__ xq  = (const float4*)xrow;   // global quad array

    float x1 = 0.f, x2 = 0.f, y1 = 0.f, y2 = 0.f, acc = 0.f;

    float4 pfA[NQ], pfB[NQ];                  // sub-chunk ping-pong prefetch
    if (wid == 0 && lane < 32) {
        #pragma unroll
        for (int i = 0; i < NQ; ++i) pfA[i] = xq[i];   // chunk 0, sub 0
    }

#define HP1(xx, oo)                                                          \
    {  float s1 = __fmaf_rn(hb0, xx, __fmul_rn(hb1, x1));                    \
       float s2 = __fmaf_rn(hb2, x2, s1); x2 = x1; x1 = xx;                  \
       float s3 = __fmaf_rn(hna1, y1, s2);                                   \
       oo = __fmaf_rn(hna2, y2, s3); y2 = y1; y1 = oo; }

// Consume USE (holds sub-chunk `s` of chunk `cc`), refill FILL from quad
// base NEXTQ (the next sub-chunk; for s=3 that's chunk cc+1 sub 0, loads
// stay in flight across the lds-only barrier).
#define W0SUB(USE, FILL, cc, s, NEXTQ)                                       \
    {                                                                        \
        float4* __restrict__ ob = (float4*)I1[(cc) & 1];                     \
        _Pragma("unroll")                                                    \
        for (int i = 0; i < NQ; ++i) {                                       \
            float4 v = USE[i];                                               \
            FILL[i] = xq[(NEXTQ) + i];                                       \
            float4 o;                                                        \
            HP1(v.x, o.x) HP1(v.y, o.y) HP1(v.z, o.z) HP1(v.w, o.w)          \
            ob[((s) * NQ + i) * 32 + ch] = o;                                \
        }                                                                    \
    }

    for (int iter = 0; iter < TOT_IT; ++iter) {
        if (wid == 0) {
            if (iter < NCHUNK && lane < 32) {
                const int c = iter;
                const int q0 = c * QPC;
                // invariant: pfA holds sub 0 of chunk c.  2-iteration pair
                // loop (NOT unrolled) preserves the A/B ping-pong parity
                // across iterations and across chunks (NSUB even).
                #pragma clang loop unroll(disable)
                for (int sp = 0; sp < 2; ++sp) {
                    const int s0 = 2 * sp;
                    W0SUB(pfA, pfB, c, s0,     q0 + (s0 + 1) * NQ)
                    W0SUB(pfB, pfA, c, s0 + 1, q0 + (s0 + 2) * NQ)
                }
                // max prefetch: c=623, sp=1 -> quads 39936..39951 ->
                // sample 159807 < 160000 (same reach as verified kernel)
            }
        } else if (wid == 1) {
            if (iter >= 1 && iter <= NCHUNK && lane < 32) {
                const int c = iter - 1;
                const float4* __restrict__ ib = (const float4*)I1[c & 1];
                float4* __restrict__ ob = (float4*)I2[c & 1];
                #pragma clang loop unroll(disable)
                for (int s = 0; s < NSUB; ++s) {
                    float4 v[NQ];
                    #pragma unroll
                    for (int i = 0; i < NQ; ++i) v[i] = ib[(s * NQ + i) * 32 + ch];
                    #pragma unroll
                    for (int i = 0; i < NQ; ++i) {
                        float4 o;
                        #define LP1(xx, oo) \
                            { float s1 = __fmaf_rn(lb0, xx, __fmul_rn(lb1, x1)); \
                              float s2 = __fmaf_rn(lb2, x2, s1); x2 = x1; x1 = xx; \
                              float s3 = __fmaf_rn(lna1, y1, s2); \
                              oo = __fmaf_rn(lna2, y2, s3); y2 = y1; y1 = oo; }
                        LP1(v[i].x, o.x) LP1(v[i].y, o.y) LP1(v[i].z, o.z) LP1(v[i].w, o.w)
                        #undef LP1
                        ob[(s * NQ + i) * 32 + ch] = o;
                    }
                }
            }
        } else {
            if (iter >= 2) {
                const int c = iter - 2;
                const bool evenHalf = (lane < 32);
                const float4* __restrict__ ib = (const float4*)I2[c & 1];
                #pragma clang loop unroll(disable)
                for (int s = 0; s < NSUB; ++s) {
                    const int u = c * NSUB + s;       // global 64-sample index
                    const int m32 = u & 31;
                    // segment j = u/16 starts at sub-chunk u when u%32==0 (even j) or 16 (odd j)
                    if ((m32 == (evenHalf ? 0 : 16)) && (u >> 4) < NSEG) {
                        x1 = 0.f; x2 = 0.f; y1 = 0.f; y2 = 0.f; acc = 0.f;
                    }
                    float4 v[NQ];
                    #pragma unroll
                    for (int i = 0; i < NQ; ++i) v[i] = ib[(s * NQ + i) * 32 + ch];
                    #pragma unroll
                    for (int i = 0; i < NQ; ++i) {
                        float s1, s2, s3, yy;
                        // s1 = fma(-2,x1,x): product exact -> bit-identical to add form
                        #define WSTEP(xx) \
                            s1 = __fmaf_rn(-2.0f, x1, xx); \
                            s2 = __fadd_rn(s1, x2); \
                            s3 = __fmaf_rn(NA1, y1, s2); \
                            yy = __fmaf_rn(NA2, y2, s3); \
                            x2 = x1; x1 = xx; y2 = y1; y1 = yy; \
                            acc = __fmaf_rn(yy, yy, acc);
                        WSTEP(v[i].x) WSTEP(v[i].y) WSTEP(v[i].z) WSTEP(v[i].w)
                        #undef WSTEP
                    }
                    // even seg ends when u%32==31; odd when u%32==15 (u>=31); j=(u-31)/16
                    const int endm = evenHalf ? 31 : 15;
                    if (m32 == endm && u >= 31) {
                        const int j = (u - 31) >> 4;
                        float e = __fmul_rn(acc, 0.00048828125f);   // /2048 exact
                        loud[((size_t)((band * 2 + src) * ROWS + ch)) * NSEG + j] =
                            __fmul_rn(10.0f, log10f(__fadd_rn(e, 1e-8f)));
                    }
                }
            }
        }
        barrier_lds_only();
    }
#undef W0SUB
#undef HP1
}

__global__ __launch_bounds__(256)
void tf_reduce_kernel(const float* __restrict__ loud, float* __restrict__ out) {
    __shared__ double sh[256];
    const int per_band = ROWS * NSEG;       // 4960
    const int npairs   = NBANDS * per_band; // 39680
    double s = 0.0;
    for (int idx = threadIdx.x; idx < npairs; idx += 256) {
        int band = idx / per_band;
        int rs   = idx - band * per_band;
        float a = loud[(size_t)(band * 2 + 0) * per_band + rs];
        float b = loud[(size_t)(band * 2 + 1) * per_band + rs];
        s += fabs((double)b - (double)a);
    }
    sh[threadIdx.x] = s;
    __syncthreads();
    for (int off = 128; off > 0; off >>= 1) {
        if (threadIdx.x < off) sh[threadIdx.x] += sh[threadIdx.x + off];
        __syncthreads();
    }
    if (threadIdx.x == 0) out[0] = (float)(sh[0] / (double)npairs);
}

// Host-side coefficients: f64 with the reference's exact expression order,
// then cast each to f32 (mirrors tuple(np.float32(v / a0) ...)).
static void mk_hp(double cutoff, float* o) {
    const double w0    = 2.0 * M_PI * cutoff / 16000.0;
    const double alpha = sin(w0) / (2.0 * 0.707);
    const double cw    = cos(w0);
    const double b0 = (1.0 + cw) / 2.0;
    const double b1 = -(1.0 + cw);
    const double b2 = (1.0 + cw) / 2.0;
    const double a0 = 1.0 + alpha;
    const double a1 = -2.0 * cw;
    const double a2 = 1.0 - alpha;
    o[0] = (float)(b0 / a0); o[1] = (float)(b1 / a0); o[2] = (float)(b2 / a0);
    o[3] = (float)(a1 / a0); o[4] = (float)(a2 / a0);
}

static void mk_lp(double cutoff, float* o) {
    const double w0    = 2.0 * M_PI * cutoff / 16000.0;
    const double alpha = sin(w0) / (2.0 * 0.707);
    const double cw    = cos(w0);
    const double b0 = (1.0 - cw) / 2.0;
    const double b1 = 1.0 - cw;
    const double b2 = (1.0 - cw) / 2.0;
    const double a0 = 1.0 + alpha;
    const double a1 = -2.0 * cw;
    const double a2 = 1.0 - alpha;
    o[0] = (float)(b0 / a0); o[1] = (float)(b1 / a0); o[2] = (float)(b2 / a0);
    o[3] = (float)(a1 / a0); o[4] = (float)(a2 / a0);
}

extern "C" void kernel_launch(void* const* d_in, const int* in_sizes, int n_in,
                              void* d_out, int out_size, void* d_ws, size_t ws_size,
                              hipStream_t stream) {
    const float* sig = (const float*)d_in[0];
    const float* wm  = (const float*)d_in[1];
    float* loud = (float*)d_ws;   // 79360 floats = 310 KiB

    AllCoefs C;
    for (int i = 0; i < NBANDS; ++i) {
        mk_hp(1000.0 * (double)i,       C.h[i]);   // low_cut  = i*1000 exactly
        mk_lp(1000.0 * (double)(i + 1), C.l[i]);   // high_cut = (i+1)*1000 exactly
    }

    tf_pipe3_kernel<<<dim3(NBANDS, 2), 192, 0, stream>>>(sig, wm, loud, C);
    tf_reduce_kernel<<<1, 256, 0, stream>>>(loud, (float*)d_out);
}

// Round 3
// 2201.822 us; speedup vs baseline: 2.4075x; 1.0787x over previous
//
#include <hip/hip_runtime.h>
#include <cmath>

#ifndef M_PI
#define M_PI 3.14159265358979323846
#endif

#define T_LEN   160000
#define NSEG    155
#define ROWS    32
#define NBANDS  8

#define CHUNK   192                  // samples per barrier interval
#define NSUB    3                    // sub-chunks of 64
#define NQ      16                   // float4 quads per sub-chunk per chain
#define QPC     48                   // quads per chunk per chain
#define NCHUNK  832                  // 192*832 = 159744 = all samples any segment uses
#define TOT_IT  (NCHUNK + 2)         // 3-stage pipeline drain
#define LOUD_FLOATS (NBANDS * 2 * ROWS * NSEG)   // 79360

struct AllCoefs {
    float h[NBANDS][5];   // b0 b1 b2 a1 a2 (a0-normalized, f32-cast like np.float32)
    float l[NBANDS][5];
};

// Workgroup barrier without the vmcnt(0) drain (only LDS carries inter-wave
// data; w0's global prefetch stays in flight across the barrier).
__device__ __forceinline__ void barrier_lds_only() {
    asm volatile("s_waitcnt lgkmcnt(0)\n\ts_barrier" ::: "memory");
}

// ============================ Fused pipeline =============================
// R3: one block per BAND (8 blocks), both sources merged into the lanes:
// 64 lanes = 2 srcs x 32 chains -> every wave issues with a FULL 64-lane
// EXEC mask (wave64 VALU is 2 cyc regardless of mask; the old 32-lane
// waves wasted half of every issue slot).  4 waves:
//   w0 : hp biquad    global x (ping-pong prefetch) -> slot c%3
//   w1 : lp biquad    IN-PLACE transform of slot (c-1)%3
//   w2 : weighting even-parity segments, all 64 chains
//   w3 : weighting odd-parity segments, all 64 chains
// 3-slot rotating LDS buffer (CHUNK=192, 3x48 KiB = 144 KiB): writer,
// in-place transformer, readers always hit distinct slots mod 3, with
// lgkm-drain barriers between iterations.
// Per-chain arithmetic ops and their ORDER are bit-identical to the
// kernel verified BIT-EXACT vs the np reference (absmax 0.0).
__global__ __launch_bounds__(256, 1)
void tf_pipe4_kernel(const float* __restrict__ sig, const float* __restrict__ wm,
                     float* __restrict__ loud, AllCoefs C) {
    __shared__ float4 I[3][QPC * 64];          // 3 x 48 KiB = 144 KiB

    const int band = blockIdx.x;
    const int tid  = threadIdx.x;
    const int wid  = tid >> 6;                 // 0..3
    const int lane = tid & 63;
    const int row  = lane & 31;                // batch row
    const int src  = lane >> 5;                // 0 = signal, 1 = watermark

    const float hb0 = C.h[band][0], hb1 = C.h[band][1], hb2 = C.h[band][2];
    const float hna1 = -C.h[band][3], hna2 = -C.h[band][4];
    const float lb0 = C.l[band][0], lb1 = C.l[band][1], lb2 = C.l[band][2];
    const float lna1 = -C.l[band][3], lna2 = -C.l[band][4];
    const float NA1 =  1.79999995231628417969f; // -np.float32(-1.8)
    const float NA2 = -0.810000002384185791f;   // -np.float32(0.81)

    const float* __restrict__ xrow = (src ? wm : sig) + (size_t)row * T_LEN;
    const float4* __restrict__ xq  = (const float4*)xrow;   // per-lane quad stream

    float x1 = 0.f, x2 = 0.f, y1 = 0.f, y2 = 0.f, acc = 0.f;

    float4 pfA[NQ], pfB[NQ];                   // sub-chunk ping-pong prefetch (w0)
    if (wid == 0) {
        #pragma unroll
        for (int i = 0; i < NQ; ++i) pfA[i] = xq[i];   // chunk 0, sub 0
    }

#define HP1(xx, oo)                                                          \
    {  float s1 = __fmaf_rn(hb0, xx, __fmul_rn(hb1, x1));                    \
       float s2 = __fmaf_rn(hb2, x2, s1); x2 = x1; x1 = xx;                  \
       float s3 = __fmaf_rn(hna1, y1, s2);                                   \
       oo = __fmaf_rn(hna2, y2, s3); y2 = y1; y1 = oo; }

#define LP1(xx, oo)                                                          \
    {  float s1 = __fmaf_rn(lb0, xx, __fmul_rn(lb1, x1));                    \
       float s2 = __fmaf_rn(lb2, x2, s1); x2 = x1; x1 = xx;                  \
       float s3 = __fmaf_rn(lna1, y1, s2);                                   \
       oo = __fmaf_rn(lna2, y2, s3); y2 = y1; y1 = oo; }

// w0 sub-chunk: consume USE (sub `S` of current chunk), refill FILL from
// quad base NEXTQ (next sub-chunk; for S=2 that's next chunk's sub 0 —
// loads stay in flight across the lds-only barrier).  USE==FILL is safe:
// v is copied before FILL[i] is overwritten.
#define W0SUB(USE, FILL, S, NEXTQ)                                           \
    {                                                                        \
        _Pragma("unroll")                                                    \
        for (int i = 0; i < NQ; ++i) {                                       \
            float4 v = USE[i];                                               \
            FILL[i] = xq[(NEXTQ) + i];                                       \
            float4 o;                                                        \
            HP1(v.x, o.x) HP1(v.y, o.y) HP1(v.z, o.z) HP1(v.w, o.w)          \
            ob[((S) * NQ + i) * 64 + lane] = o;                              \
        }                                                                    \
    }

// w1 sub-chunk: in-place lp transform of sub `S` (read all quads into
// registers, then overwrite the same addresses).
#define W1SUB(S)                                                             \
    {                                                                        \
        float4 v[NQ];                                                        \
        _Pragma("unroll")                                                    \
        for (int i = 0; i < NQ; ++i) v[i] = b[((S) * NQ + i) * 64 + lane];   \
        _Pragma("unroll")                                                    \
        for (int i = 0; i < NQ; ++i) {                                       \
            float4 o;                                                        \
            LP1(v[i].x, o.x) LP1(v[i].y, o.y) LP1(v[i].z, o.z) LP1(v[i].w, o.w) \
            b[((S) * NQ + i) * 64 + lane] = o;                               \
        }                                                                    \
    }

// weight sub-chunk for parity EV (true = even segments): identical
// reset/end conditions and arithmetic to the verified kernel.
#define WGSUB(S)                                                             \
    {                                                                        \
        const int u = c * NSUB + (S);          /* global 64-sample index */  \
        const int m32 = u & 31;                                              \
        if ((m32 == (EV ? 0 : 16)) && (u >> 4) < NSEG) {                     \
            x1 = 0.f; x2 = 0.f; y1 = 0.f; y2 = 0.f; acc = 0.f;               \
        }                                                                    \
        float4 v[NQ];                                                        \
        _Pragma("unroll")                                                    \
        for (int i = 0; i < NQ; ++i) v[i] = b[((S) * NQ + i) * 64 + lane];   \
        _Pragma("unroll")                                                    \
        for (int i = 0; i < NQ; ++i) {                                       \
            float s1, s2, s3, yy;                                            \
            /* s1 = fma(-2,x1,x): product exact -> bit-identical to add form */ \
            WSTEP(v[i].x) WSTEP(v[i].y) WSTEP(v[i].z) WSTEP(v[i].w)          \
        }                                                                    \
        const int endm = EV ? 31 : 15;                                       \
        if (m32 == endm && u >= 31) {                                        \
            const int j = (u - 31) >> 4;                                     \
            float e = __fmul_rn(acc, 0.00048828125f);   /* /2048 exact */    \
            loud[((size_t)((band * 2 + src) * ROWS + row)) * NSEG + j] =     \
                __fmul_rn(10.0f, log10f(__fadd_rn(e, 1e-8f)));               \
        }                                                                    \
    }

#define WSTEP(xx) \
    s1 = __fmaf_rn(-2.0f, x1, xx); \
    s2 = __fadd_rn(s1, x2); \
    s3 = __fmaf_rn(NA1, y1, s2); \
    yy = __fmaf_rn(NA2, y2, s3); \
    x2 = x1; x1 = xx; y2 = y1; y1 = yy; \
    acc = __fmaf_rn(yy, yy, acc);

    for (int iter = 0; iter < TOT_IT; ++iter) {
        if (wid == 0) {
            if (iter < NCHUNK) {
                const int c = iter;
                const int q0 = c * QPC;
                float4* __restrict__ ob = I[c % 3];
                // invariant: pfA holds sub 0 of chunk c; after the (A,B),
                // (B,A),(A,A) sequence pfA holds sub 0 of chunk c+1.
                W0SUB(pfA, pfB, 0, q0 + 1 * NQ)
                W0SUB(pfB, pfA, 1, q0 + 2 * NQ)
                W0SUB(pfA, pfA, 2, q0 + 3 * NQ)
                // max prefetch: c=831 -> quads 39936..39951 -> sample
                // 159807 < 160000 (in-bounds read)
            }
        } else if (wid == 1) {
            const int c = iter - 1;
            if (c >= 0 && c < NCHUNK) {
                float4* __restrict__ b = I[c % 3];
                W1SUB(0) W1SUB(1) W1SUB(2)
            }
        } else {
            const bool EV = (wid == 2);        // wave-uniform
            const int c = iter - 2;
            if (c >= 0 && c < NCHUNK) {
                const float4* __restrict__ b = I[c % 3];
                WGSUB(0) WGSUB(1) WGSUB(2)
            }
        }
        barrier_lds_only();
    }
#undef WSTEP
#undef WGSUB
#undef W1SUB
#undef W0SUB
#undef LP1
#undef HP1
}

__global__ __launch_bounds__(256)
void tf_reduce_kernel(const float* __restrict__ loud, float* __restrict__ out) {
    __shared__ double sh[256];
    const int per_band = ROWS * NSEG;       // 4960
    const int npairs   = NBANDS * per_band; // 39680
    double s = 0.0;
    for (int idx = threadIdx.x; idx < npairs; idx += 256) {
        int band = idx / per_band;
        int rs   = idx - band * per_band;
        float a = loud[(size_t)(band * 2 + 0) * per_band + rs];
        float b = loud[(size_t)(band * 2 + 1) * per_band + rs];
        s += fabs((double)b - (double)a);
    }
    sh[threadIdx.x] = s;
    __syncthreads();
    for (int off = 128; off > 0; off >>= 1) {
        if (threadIdx.x < off) sh[threadIdx.x] += sh[threadIdx.x + off];
        __syncthreads();
    }
    if (threadIdx.x == 0) out[0] = (float)(sh[0] / (double)npairs);
}

// Host-side coefficients: f64 with the reference's exact expression order,
// then cast each to f32 (mirrors tuple(np.float32(v / a0) ...)).
static void mk_hp(double cutoff, float* o) {
    const double w0    = 2.0 * M_PI * cutoff / 16000.0;
    const double alpha = sin(w0) / (2.0 * 0.707);
    const double cw    = cos(w0);
    const double b0 = (1.0 + cw) / 2.0;
    const double b1 = -(1.0 + cw);
    const double b2 = (1.0 + cw) / 2.0;
    const double a0 = 1.0 + alpha;
    const double a1 = -2.0 * cw;
    const double a2 = 1.0 - alpha;
    o[0] = (float)(b0 / a0); o[1] = (float)(b1 / a0); o[2] = (float)(b2 / a0);
    o[3] = (float)(a1 / a0); o[4] = (float)(a2 / a0);
}

static void mk_lp(double cutoff, float* o) {
    const double w0    = 2.0 * M_PI * cutoff / 16000.0;
    const double alpha = sin(w0) / (2.0 * 0.707);
    const double cw    = cos(w0);
    const double b0 = (1.0 - cw) / 2.0;
    const double b1 = 1.0 - cw;
    const double b2 = (1.0 - cw) / 2.0;
    const double a0 = 1.0 + alpha;
    const double a1 = -2.0 * cw;
    const double a2 = 1.0 - alpha;
    o[0] = (float)(b0 / a0); o[1] = (float)(b1 / a0); o[2] = (float)(b2 / a0);
    o[3] = (float)(a1 / a0); o[4] = (float)(a2 / a0);
}

extern "C" void kernel_launch(void* const* d_in, const int* in_sizes, int n_in,
                              void* d_out, int out_size, void* d_ws, size_t ws_size,
                              hipStream_t stream) {
    const float* sig = (const float*)d_in[0];
    const float* wm  = (const float*)d_in[1];
    float* loud = (float*)d_ws;   // 79360 floats = 310 KiB

    AllCoefs C;
    for (int i = 0; i < NBANDS; ++i) {
        mk_hp(1000.0 * (double)i,       C.h[i]);   // low_cut  = i*1000 exactly
        mk_lp(1000.0 * (double)(i + 1), C.l[i]);   // high_cut = (i+1)*1000 exactly
    }

    tf_pipe4_kernel<<<dim3(NBANDS), 256, 0, stream>>>(sig, wm, loud, C);
    tf_reduce_kernel<<<1, 256, 0, stream>>>(loud, (float*)d_out);
}